// Round 2
// baseline (6575.407 us; speedup 1.0000x reference)
//
#include <hip/hip_runtime.h>
#include <cstddef>

#define H_FEAT 50
#define W_FEAT 76
#define C_FEAT 256
#define HWSZ (H_FEAT*W_FEAT)
#define B_IMG 2
#define P_PROP 512
#define NROI (B_IMG*P_PROP)
#define DIN 12544            // 256*49
#define REP 4096
#define NCLS 81
#define NFLAT (P_PROP*(NCLS-1)) // 40960
#define PREK 1000
#define NDET 100
#define BBOX_CLIP_D 4.135166556742356

// ---------------- NCHW -> NHWC transpose (f32) ----------------
__global__ void __launch_bounds__(256) transpose_kernel(const float* __restrict__ in, float* __restrict__ out) {
  __shared__ float tile[32][33];
  int b = blockIdx.z;
  int hw0 = blockIdx.x * 32, c0 = blockIdx.y * 32;
  int tx = threadIdx.x, ty = threadIdx.y;
#pragma unroll
  for (int i = 0; i < 4; i++) {
    int c = c0 + ty + i*8;
    int hw = hw0 + tx;
    float v = (hw < HWSZ) ? in[((size_t)(b*C_FEAT + c))*HWSZ + hw] : 0.0f;
    tile[ty + i*8][tx] = v;
  }
  __syncthreads();
#pragma unroll
  for (int i = 0; i < 4; i++) {
    int hw = hw0 + ty + i*8;
    int c = c0 + tx;
    if (hw < HWSZ) out[((size_t)(b*HWSZ + hw))*C_FEAT + c] = tile[tx][ty + i*8];
  }
}

// ---------------- ROI align, f64 internal math, AT output ----------------
template<typename AT>
__global__ void __launch_bounds__(256) roi_kernel(const float* __restrict__ nhwc,
                                                  const float* __restrict__ props,
                                                  AT* __restrict__ X0) {
  int n = blockIdx.x;
  int b = n >> 9;
  __shared__ int sy0[14], sy1[14], sx0[14], sx1[14];
  __shared__ double sly[14], slx[14], svy[14], svx[14];
  int tid = threadIdx.x;
  if (tid < 28) {
    int s = (tid < 14) ? tid : (tid - 14);
    bool isy = tid < 14;
    double p0 = (double)props[n*4 + (isy ? 1 : 0)];
    double p1 = (double)props[n*4 + (isy ? 3 : 2)];
    double lim = isy ? (double)H_FEAT : (double)W_FEAT;
    int maxi = isy ? (H_FEAT - 1) : (W_FEAT - 1);
    double a = p0 * 0.0625;
    double bc = p1 * 0.0625;
    double r = fmax(bc - a, 1.0);
    double t = ((double)s + 0.5) / 14.0;
    double pos = a + t * r;
    double valid = (pos >= -1.0 && pos <= lim) ? 1.0 : 0.0;
    double pc = fmin(fmax(pos, 0.0), lim - 1.0);
    int i0 = (int)floor(pc);
    double l = pc - (double)i0;
    int i1 = min(i0 + 1, maxi);
    if (isy) { sy0[s]=i0; sy1[s]=i1; sly[s]=l; svy[s]=valid; }
    else     { sx0[s]=i0; sx1[s]=i1; slx[s]=l; svx[s]=valid; }
  }
  __syncthreads();
  int c = tid;
  const float* F = nhwc + (size_t)b * HWSZ * C_FEAT + c;
  AT* outp = X0 + (size_t)n * DIN + (size_t)c * 49;
  for (int ph = 0; ph < 7; ph++) {
    for (int pw = 0; pw < 7; pw++) {
      double acc = 0.0;
#pragma unroll
      for (int dy = 0; dy < 2; dy++) {
#pragma unroll
        for (int dx = 0; dx < 2; dx++) {
          int iy = ph*2 + dy, ix = pw*2 + dx;
          double ly = sly[iy], lx = slx[ix];
          double hy = 1.0 - ly, hx = 1.0 - lx;
          int y0 = sy0[iy], y1 = sy1[iy], x0 = sx0[ix], x1 = sx1[ix];
          double f00 = (double)F[(size_t)((y0*W_FEAT + x0) << 8)];
          double f01 = (double)F[(size_t)((y0*W_FEAT + x1) << 8)];
          double f10 = (double)F[(size_t)((y1*W_FEAT + x0) << 8)];
          double f11 = (double)F[(size_t)((y1*W_FEAT + x1) << 8)];
          double v = hy*hx*f00 + hy*lx*f01 + ly*hx*f10 + ly*lx*f11;
          acc += v * (svy[iy] * svx[ix]);
        }
      }
      outp[ph*7 + pw] = (AT)(acc * 0.25);
    }
  }
}

// ---------------- mid GEMM: AT activations, f32 weights, f64 accumulate ----------------
// BM=128 BN=64 BK=16, 256 threads, 8x4 per thread.
template<typename AT>
__global__ void __launch_bounds__(256) gemm_mid_kernel(const AT* __restrict__ A,
    const float* __restrict__ W, const float* __restrict__ bias,
    AT* __restrict__ C, int N, int K, int relu)
{
  __shared__ __align__(16) AT As[16][132];
  __shared__ __align__(16) float Bs[16][68];
  int m0 = blockIdx.y * 128, n0 = blockIdx.x * 64;
  int tid = threadIdx.x;
  int tx = tid & 15, ty = tid >> 4;
  double acc[8][4];
#pragma unroll
  for (int i=0;i<8;i++)
#pragma unroll
    for (int j=0;j<4;j++) acc[i][j]=0.0;

  for (int k0 = 0; k0 < K; k0 += 16) {
#pragma unroll
    for (int i = 0; i < 8; i++) {
      int e = tid + i*256;
      int r = e >> 4, kk = e & 15;
      As[kk][r] = A[(size_t)(m0 + r)*K + (k0 + kk)];
    }
#pragma unroll
    for (int i = 0; i < 4; i++) {
      int e = tid + i*256;
      int r = e >> 6, c = e & 63;
      Bs[r][c] = W[(size_t)(k0 + r)*N + (n0 + c)];
    }
    __syncthreads();
#pragma unroll
    for (int kk = 0; kk < 16; kk++) {
      double av[8], bv[4];
#pragma unroll
      for (int i=0;i<8;i++) av[i] = (double)As[kk][ty*8+i];
#pragma unroll
      for (int j=0;j<4;j++) bv[j] = (double)Bs[kk][tx*4+j];
#pragma unroll
      for (int i=0;i<8;i++)
#pragma unroll
        for (int j=0;j<4;j++)
          acc[i][j] = fma(av[i], bv[j], acc[i][j]);
    }
    __syncthreads();
  }
#pragma unroll
  for (int i=0;i<8;i++) {
    int row = m0 + ty*8 + i;
#pragma unroll
    for (int j=0;j<4;j++) {
      int col = n0 + tx*4 + j;
      double v = acc[i][j] + (double)bias[col];
      if (relu) v = v > 0.0 ? v : 0.0;
      C[(size_t)row*N + col] = (AT)v;
    }
  }
}

// ---------------- head GEMM: AT activations, f64 accumulate, dual f32/f64 store ----------------
// BM=64 BN=32 BK=32, 256 threads.
template<typename AT>
__global__ void __launch_bounds__(256) gemm_head_kernel(const AT* __restrict__ A,
    const float* __restrict__ W, const float* __restrict__ bias,
    float* __restrict__ Cf, double* __restrict__ Cd, int N, int K)
{
  __shared__ AT As[32][66];
  __shared__ float Bs[32][33];
  int n0 = blockIdx.x * 32, m0 = blockIdx.y * 64;
  int tid = threadIdx.x;
  int tx = tid & 15, ty = tid >> 4;
  double acc[4][2];
#pragma unroll
  for (int i=0;i<4;i++) { acc[i][0]=0.0; acc[i][1]=0.0; }
  for (int k0 = 0; k0 < K; k0 += 32) {
#pragma unroll
    for (int i = 0; i < 8; i++) {
      int e = tid + i*256;
      int r = e >> 5, kk = e & 31;
      As[kk][r] = A[(size_t)(m0 + r)*K + k0 + kk];
    }
#pragma unroll
    for (int i = 0; i < 4; i++) {
      int e = tid + i*256;
      int r = e >> 5, c = e & 31;
      int col = n0 + c;
      Bs[r][c] = (col < N) ? W[(size_t)(k0 + r)*N + col] : 0.0f;
    }
    __syncthreads();
#pragma unroll 8
    for (int kk = 0; kk < 32; kk++) {
      double b0 = (double)Bs[kk][tx*2], b1 = (double)Bs[kk][tx*2+1];
#pragma unroll
      for (int i = 0; i < 4; i++) {
        double a = (double)As[kk][ty*4+i];
        acc[i][0] = fma(a, b0, acc[i][0]);
        acc[i][1] = fma(a, b1, acc[i][1]);
      }
    }
    __syncthreads();
  }
#pragma unroll
  for (int i = 0; i < 4; i++) {
    int row = m0 + ty*4 + i;
#pragma unroll
    for (int j = 0; j < 2; j++) {
      int col = n0 + tx*2 + j;
      if (col < N) {
        double v = acc[i][j] + (double)bias[col];
        Cf[(size_t)row*N + col] = (float)v;
        Cd[(size_t)row*N + col] = v;
      }
    }
  }
}

// ---------------- softmax (f64), one row per thread ----------------
__global__ void __launch_bounds__(256) softmax_f64_kernel(const double* __restrict__ logits_d,
                                                          double* __restrict__ fscores_d) {
  int row = blockIdx.x * 256 + threadIdx.x;   // < 1024
  const double* L = logits_d + (size_t)row * NCLS;
  double m = L[0];
  for (int i = 1; i < NCLS; i++) m = fmax(m, L[i]);
  double tot = 0.0;
  for (int i = 0; i < NCLS; i++) tot += exp(L[i] - m);
  int img = row >> 9, p = row & 511;
  double* o = fscores_d + (size_t)img*NFLAT + (size_t)p*80;
  for (int c = 1; c < NCLS; c++) o[c-1] = exp(L[c] - m) / tot;
}

// ---------------- box decode + clip (f64) ----------------
__global__ void __launch_bounds__(256) decode_f64_kernel(const double* __restrict__ breg_d,
    const float* __restrict__ props, const int* __restrict__ imh_p, const int* __restrict__ imw_p,
    double* __restrict__ fboxes_d) {
  int g = blockIdx.x * 256 + threadIdx.x;   // < 81920
  int img = g / NFLAT;
  int f = g - img*NFLAT;
  int p = f / 80;
  int c = (f - p*80) + 1;
  int row = img*P_PROP + p;
  const float* pr = props + (size_t)row*4;
  double x1p = (double)pr[0], y1p = (double)pr[1], x2p = (double)pr[2], y2p = (double)pr[3];
  const double* d = breg_d + (size_t)row*(NCLS*4) + c*4;
  double w = x2p - x1p, h = y2p - y1p;
  double cx = x1p + 0.5*w, cy = y1p + 0.5*h;
  double dx = d[0], dy = d[1];
  double dw = fmin(fmax(d[2], -BBOX_CLIP_D), BBOX_CLIP_D);
  double dh = fmin(fmax(d[3], -BBOX_CLIP_D), BBOX_CLIP_D);
  double pcx = dx*w + cx, pcy = dy*h + cy;
  double pw = exp(dw)*w, ph = exp(dh)*h;
  double imw = (double)imw_p[0], imh = (double)imh_p[0];
  double bx1 = fmin(fmax(pcx - 0.5*pw, 0.0), imw);
  double by1 = fmin(fmax(pcy - 0.5*ph, 0.0), imh);
  double bx2 = fmin(fmax(pcx + 0.5*pw, 0.0), imw);
  double by2 = fmin(fmax(pcy + 0.5*ph, 0.0), imh);
  double* o = fboxes_d + (size_t)g*4;
  o[0]=bx1; o[1]=by1; o[2]=bx2; o[3]=by2;
}

// ---------------- per-image exact top-1000 (f64 keys) + NMS (f64) + top-100 ----------------
__global__ void __launch_bounds__(1024) topk_nms_kernel(
    const double* __restrict__ fscores_d, const double* __restrict__ fboxes_d,
    unsigned long long* __restrict__ Mws,
    float* __restrict__ det_boxes, float* __restrict__ det_scores, float* __restrict__ det_labels)
{
  int img = blockIdx.x, tid = threadIdx.x;
  const double* sc = fscores_d + (size_t)img*NFLAT;
  __shared__ __align__(16) double bbx[PREK*4];                 // 32 KB; phase-1 alias below
  unsigned long long* arr = (unsigned long long*)bbx;           // [0,2048) keys, 16 KB
  unsigned* aidx = (unsigned*)(bbx + 2048);                     // 2048 idx, 8 KB
  __shared__ double ssd[PREK];
  __shared__ int slab[PREK];
  __shared__ int sidx[PREK];
  __shared__ unsigned hist[256];
  __shared__ unsigned long long keep0w[16], keepw[16];
  __shared__ unsigned long long sh_prefix;
  __shared__ unsigned sh_R, sh_cnt;
  __shared__ int sh_ktot;

  // ---- 64-bit radix select: exact bit pattern of the 1000th-largest score
  unsigned long long prefix = 0; unsigned R = PREK;
  for (int pass = 0; pass < 8; pass++) {
    int shift = 56 - 8*pass;
    if (tid < 256) hist[tid] = 0;
    __syncthreads();
    for (int i = tid; i < NFLAT; i += 1024) {
      unsigned long long k = __double_as_longlong(sc[i]);  // scores > 0: monotone as u64
      bool match = (pass == 0) || ((k >> (shift + 8)) == (prefix >> (shift + 8)));
      if (match) atomicAdd(&hist[(unsigned)(k >> shift) & 255u], 1u);
    }
    __syncthreads();
    if (tid == 0) {
      unsigned cum = 0; int d = 255;
      for (;;) {
        unsigned h = hist[d];
        if (cum + h >= R || d == 0) break;
        cum += h; d--;
      }
      sh_prefix = prefix | ((unsigned long long)d << shift);
      sh_R = R - cum;
    }
    __syncthreads();
    prefix = sh_prefix; R = sh_R;
    __syncthreads();
  }
  unsigned long long T = prefix;

  // ---- gather all keys >= T
  if (tid == 0) sh_cnt = 0;
  __syncthreads();
  for (int i = tid; i < NFLAT; i += 1024) {
    unsigned long long k = __double_as_longlong(sc[i]);
    if (k >= T) {
      unsigned pos = atomicAdd(&sh_cnt, 1u);
      if (pos < 2048) { arr[pos] = k; aidx[pos] = (unsigned)i; }
    }
  }
  __syncthreads();
  int ncand = (int)min(sh_cnt, 2048u);
  for (int i = tid; i < 2048; i += 1024) if (i >= ncand) { arr[i] = 0ull; aidx[i] = 0xFFFFFFFFu; }
  __syncthreads();

  // ---- bitonic sort 2048 entries by (key desc, idx asc)
  for (unsigned k2 = 2; k2 <= 2048; k2 <<= 1) {
    for (unsigned j = k2 >> 1; j > 0; j >>= 1) {
      unsigned i = tid + (tid & ~(j - 1));
      unsigned ixj = i | j;
      unsigned long long ka = arr[i], kb = arr[ixj];
      unsigned ia = aidx[i], ib = aidx[ixj];
      bool up = ((i & k2) == 0);
      bool after_ab = (ka < kb) || (ka == kb && ia > ib);   // a ranks after b
      bool after_ba = (kb < ka) || (kb == ka && ib > ia);
      if (up ? after_ab : after_ba) { arr[i]=kb; arr[ixj]=ka; aidx[i]=ib; aidx[ixj]=ia; }
      __syncthreads();
    }
  }

  // ---- extract top-1000 into registers (arr/aidx alias bbx and get overwritten next)
  unsigned long long myk = (tid < PREK) ? arr[tid] : 0ull;
  unsigned myidx = (tid < PREK) ? aidx[tid] : 0u;
  if (tid < 16) keep0w[tid] = 0ull;
  __syncthreads();
  if (tid < PREK) {
    double s = __longlong_as_double(myk);
    int lab = (int)(myidx % 80u) + 1;
    const double* bp = fboxes_d + ((size_t)img*NFLAT + myidx)*4;
    double off = (double)lab * 10000.0;
    bbx[tid*4+0] = bp[0] + off;
    bbx[tid*4+1] = bp[1] + off;
    bbx[tid*4+2] = bp[2] + off;
    bbx[tid*4+3] = bp[3] + off;
    ssd[tid] = s; slab[tid] = lab; sidx[tid] = (int)myidx;
    if (s > 0.05) atomicOr(&keep0w[tid >> 6], 1ull << (tid & 63));
  }
  __syncthreads();

  // ---- suppression bit-matrix M[i][word]: bit j iff (j>i, same label, iou>0.3), all f64
  for (int w = tid; w < PREK*16; w += 1024) {
    int i = w >> 4, wd = w & 15;
    double ax1 = bbx[i*4+0], ay1 = bbx[i*4+1], ax2 = bbx[i*4+2], ay2 = bbx[i*4+3];
    double areaA = (ax2-ax1)*(ay2-ay1);
    int li = slab[i];
    unsigned long long bits = 0;
    int jbase = wd << 6;
#pragma unroll 1
    for (int bit = 0; bit < 64; bit++) {
      int j = jbase + bit;
      if (j >= PREK) break;
      if (j <= i || slab[j] != li) continue;
      double bx1 = bbx[j*4+0], by1 = bbx[j*4+1], bx2 = bbx[j*4+2], by2 = bbx[j*4+3];
      double areaB = (bx2-bx1)*(by2-by1);
      double ltx = fmax(ax1,bx1), lty = fmax(ay1,by1);
      double rbx = fmin(ax2,bx2), rby = fmin(ay2,by2);
      double wx = fmax(rbx-ltx, 0.0), wy = fmax(rby-lty, 0.0);
      double inter = wx*wy;
      double iou = inter / (areaA + areaB - inter + 1e-9);
      if (iou > 0.3) bits |= (1ull << bit);
    }
    Mws[(size_t)img*(PREK*16) + w] = bits;
  }
  __syncthreads();

  // ---- sequential greedy pass on wave 0 (16-lane 1000-bit removed mask, prefetched rows)
  if (tid < 64) {
    unsigned long long rem = 0;
    if (tid < 16) rem = ~keep0w[tid];   // bits >= PREK auto-removed (keep0w never set there)
    const unsigned long long* Mrow = Mws + (size_t)img*(PREK*16);
    unsigned long long mcur = (tid < 16) ? Mrow[tid] : 0ull;
    for (int i = 0; i < PREK; i++) {
      unsigned long long mnext = (i+1 < PREK && tid < 16) ? Mrow[(size_t)(i+1)*16 + tid] : 0ull;
      unsigned long long wv = __shfl(rem, i >> 6);
      if (!((wv >> (i & 63)) & 1ull)) rem |= mcur;
      mcur = mnext;
    }
    if (tid < 16) keepw[tid] = ~rem;
  }
  __syncthreads();
  if (tid == 0) {
    int t = 0;
    for (int w2 = 0; w2 < 16; w2++) t += __popcll(keepw[w2]);
    sh_ktot = t;
  }
  __syncthreads();

  // ---- final top-100: kept entries in order, then -1 fillers (not-kept in order)
  if (tid < PREK) {
    int w2 = tid >> 6, bit = tid & 63;
    bool kept = (keepw[w2] >> bit) & 1ull;
    int rank = 0;
    for (int ww = 0; ww < w2; ww++) rank += __popcll(keepw[ww]);
    rank += __popcll(keepw[w2] & ((1ull << bit) - 1ull));
    int ktot = sh_ktot;
    int slot = kept ? rank : (ktot + (tid - rank));
    if (slot < NDET) {
      int oidx = img*NDET + slot;
      const double* bp = fboxes_d + ((size_t)img*NFLAT + sidx[tid])*4;
      det_boxes[oidx*4+0] = (float)bp[0];
      det_boxes[oidx*4+1] = (float)bp[1];
      det_boxes[oidx*4+2] = (float)bp[2];
      det_boxes[oidx*4+3] = (float)bp[3];
      det_scores[oidx] = kept ? (float)ssd[tid] : -1.0f;
      det_labels[oidx] = (float)slab[tid];
    }
  }
}

// ---------------- launch ----------------
template<typename AT>
static void run_pipeline(const float* features, const float* proposals,
                         const float* fc6_w, const float* fc6_b,
                         const float* fc7_w, const float* fc7_b,
                         const float* cls_w, const float* cls_b,
                         const float* bbox_w, const float* bbox_b,
                         const int* im_h, const int* im_w,
                         float* logits_out, float* breg_out,
                         float* det_boxes, float* det_scores, float* det_labels,
                         char* wsb, hipStream_t stream)
{
  // fixed f64 region
  double* logits_d  = (double*)(wsb);                         // 1024*81
  double* breg_d    = (double*)(wsb + 663552);                // 1024*324
  double* fscores_d = (double*)(wsb + 3317760);               // 81920
  double* fboxes_d  = (double*)(wsb + 3973120);               // 327680*... (4 per entry)
  unsigned long long* Mws = (unsigned long long*)(wsb + 6594560); // 32000
  float* nhwc       = (float*)(wsb + 6850560);                // 1,945,600 f32
  char*  actb       = wsb + 14632960;
  AT* X0 = (AT*)actb;                                          // NROI*DIN
  AT* X1 = (AT*)(actb + (size_t)NROI*DIN*sizeof(AT));          // NROI*REP
  AT* X2 = X0;  // pooled dead after fc6

  transpose_kernel<<<dim3((HWSZ+31)/32, C_FEAT/32, B_IMG), dim3(32,8,1), 0, stream>>>(features, nhwc);
  roi_kernel<AT><<<dim3(NROI), dim3(C_FEAT), 0, stream>>>(nhwc, proposals, X0);
  gemm_mid_kernel<AT><<<dim3(REP/64, NROI/128), dim3(256), 0, stream>>>(X0, fc6_w, fc6_b, X1, REP, DIN, 1);
  gemm_mid_kernel<AT><<<dim3(REP/64, NROI/128), dim3(256), 0, stream>>>(X1, fc7_w, fc7_b, X2, REP, REP, 1);
  gemm_head_kernel<AT><<<dim3((NCLS+31)/32, NROI/64), dim3(256), 0, stream>>>(X2, cls_w, cls_b, logits_out, logits_d, NCLS, REP);
  gemm_head_kernel<AT><<<dim3((NCLS*4+31)/32, NROI/64), dim3(256), 0, stream>>>(X2, bbox_w, bbox_b, breg_out, breg_d, NCLS*4, REP);
  softmax_f64_kernel<<<dim3(NROI/256), dim3(256), 0, stream>>>(logits_d, fscores_d);
  decode_f64_kernel<<<dim3((B_IMG*NFLAT)/256), dim3(256), 0, stream>>>(breg_d, proposals, im_h, im_w, fboxes_d);
  topk_nms_kernel<<<dim3(B_IMG), dim3(1024), 0, stream>>>(fscores_d, fboxes_d, Mws, det_boxes, det_scores, det_labels);
}

extern "C" void kernel_launch(void* const* d_in, const int* in_sizes, int n_in,
                              void* d_out, int out_size, void* d_ws, size_t ws_size,
                              hipStream_t stream) {
  const float* features  = (const float*)d_in[0];
  const float* proposals = (const float*)d_in[1];
  const float* fc6_w = (const float*)d_in[2];
  const float* fc6_b = (const float*)d_in[3];
  const float* fc7_w = (const float*)d_in[4];
  const float* fc7_b = (const float*)d_in[5];
  const float* cls_w = (const float*)d_in[6];
  const float* cls_b = (const float*)d_in[7];
  const float* bbox_w = (const float*)d_in[8];
  const float* bbox_b = (const float*)d_in[9];
  const int* im_h = (const int*)d_in[10];
  const int* im_w = (const int*)d_in[11];

  float* out = (float*)d_out;
  float* logits_out = out;                                  // 1024*81
  float* breg_out   = out + (size_t)NROI*NCLS;              // 1024*324
  float* det_boxes  = breg_out + (size_t)NROI*NCLS*4;       // 2*100*4
  float* det_scores = det_boxes + (size_t)B_IMG*NDET*4;     // 2*100
  float* det_labels = det_scores + (size_t)B_IMG*NDET;      // 2*100

  char* wsb = (char*)d_ws;
  size_t base = 14632960;  // f64 dets + Mws + nhwc
  size_t need64 = base + ((size_t)NROI*DIN + (size_t)NROI*REP) * 8;
  if (ws_size >= need64) {
    run_pipeline<double>(features, proposals, fc6_w, fc6_b, fc7_w, fc7_b, cls_w, cls_b,
                         bbox_w, bbox_b, im_h, im_w,
                         logits_out, breg_out, det_boxes, det_scores, det_labels, wsb, stream);
  } else {
    run_pipeline<float>(features, proposals, fc6_w, fc6_b, fc7_w, fc7_b, cls_w, cls_b,
                        bbox_w, bbox_b, im_h, im_w,
                        logits_out, breg_out, det_boxes, det_scores, det_labels, wsb, stream);
  }
}